// Round 7
// baseline (343.162 us; speedup 1.0000x reference)
//
#include <hip/hip_runtime.h>
#include <hip/hip_bf16.h>

// WinMSA for MI355X (gfx950), v7: 3-kernel pipeline through d_ws.
//   K1: qkv = X @ Wqkv + b   (v5 shape: 128 rows/block, grid 1568; NEW: outputs
//       packed to bf16 regs per chunk, global stores flushed only twice so the
//       per-chunk __syncthreads no longer drains HBM store round-trips)
//   K2: per-window attention (rotated V-scatter, 3-way instead of 24-way conflicts)
//   K3: out = AO @ Wo + bo   (v5 version: 128 rows/block, grid 1568)

typedef __attribute__((ext_vector_type(4))) float f32x4;
typedef __attribute__((ext_vector_type(8))) short bf16x8;
typedef __attribute__((ext_vector_type(4))) unsigned short u16x4;

#define SCALE 0.17677669529663689f  // 32^-0.5
#define MFMA(a, b, acc) __builtin_amdgcn_mfma_f32_16x16x32_bf16(a, b, acc, 0, 0, 0)

__device__ __forceinline__ unsigned short f2bf(float f) {
  union { float f; unsigned int u; } v; v.f = f;
  return (unsigned short)((v.u + 0x7FFFu + ((v.u >> 16) & 1u)) >> 16);  // RNE
}

// Pre-kernel: transpose weights to bf16 [out][in].
__global__ void wprep(const float* __restrict__ Wqkv, const float* __restrict__ Wo,
                      unsigned short* __restrict__ WqkvT, unsigned short* __restrict__ WoT) {
  int i = blockIdx.x * 256 + threadIdx.x;
  if (i < 576 * 192) { int n = i / 192, k = i % 192; WqkvT[i] = f2bf(Wqkv[k * 576 + n]); }
  if (i < 192 * 192) { int n = i / 192, k = i % 192; WoT[i]   = f2bf(Wo[k * 192 + n]); }
}

// ---------------- K1: qkv GEMM, 128 rows/block, deferred stores ----------------
__global__ __launch_bounds__(512, 4)
void qkv_gemm(const float* __restrict__ X, const unsigned short* __restrict__ WqkvT,
              const float* __restrict__ bqkv, unsigned short* __restrict__ qkv) {
  __shared__ __align__(16) unsigned short Bs[2][64 * 200];  // weight chunk dbuf, padded
  __shared__ __align__(16) unsigned short scr[8][16 * 72];  // per-wave store bounce

  const int tid = threadIdx.x, w8 = tid >> 6, lane = tid & 63;
  const int g = lane >> 4, c = lane & 15;
  const size_t bm = (size_t)blockIdx.x * 128;
  const f32x4 z = {0.f, 0.f, 0.f, 0.f};

  // A-fragments: 16 rows of X per wave, f32 -> bf16, register-resident
  bf16x8 af[6];
  {
    const float* xr = X + (bm + w8 * 16 + c) * 192;
    #pragma unroll
    for (int ks = 0; ks < 6; ++ks) {
      f32x4 lo = *(const f32x4*)(xr + ks * 32 + g * 8);
      f32x4 hi = *(const f32x4*)(xr + ks * 32 + g * 8 + 4);
      bf16x8 a;
      a[0] = (short)f2bf(lo[0]); a[1] = (short)f2bf(lo[1]);
      a[2] = (short)f2bf(lo[2]); a[3] = (short)f2bf(lo[3]);
      a[4] = (short)f2bf(hi[0]); a[5] = (short)f2bf(hi[1]);
      a[6] = (short)f2bf(hi[2]); a[7] = (short)f2bf(hi[3]);
      af[ks] = a;
    }
  }

  // stage chunk 0
  uint4 st[3];
  #pragma unroll
  for (int jj = 0; jj < 3; ++jj) {
    int j = tid + jj * 512;
    st[jj] = *(const uint4*)(WqkvT + (j / 24) * 192 + (j % 24) * 8);
  }
  #pragma unroll
  for (int jj = 0; jj < 3; ++jj) {
    int j = tid + jj * 512;
    *(uint4*)(&Bs[0][(j / 24) * 200 + (j % 24) * 8]) = st[jj];
  }
  __syncthreads();

  unsigned short* sw = scr[w8];
  u16x4 pk[5][4];  // packed bf16 outputs (static indices via full unroll)

  // flush one chunk's packed output: bounce -> coalesced 16B stores
  auto flush = [&](int nca, const u16x4* pkc) {
    #pragma unroll
    for (int nf = 0; nf < 4; ++nf)
      #pragma unroll
      for (int r = 0; r < 4; ++r)
        sw[(4 * g + r) * 72 + nf * 16 + c] = pkc[nf][r];
    uint4 o0 = *(const uint4*)(sw + c * 72 + g * 8);
    uint4 o1 = *(const uint4*)(sw + c * 72 + 32 + g * 8);
    unsigned short* qp = qkv + (bm + w8 * 16 + c) * 576 + nca * 64;
    *(uint4*)(qp + g * 8)      = o0;
    *(uint4*)(qp + 32 + g * 8) = o1;
  };

  #pragma unroll
  for (int nc = 0; nc < 9; ++nc) {
    const int cur = nc & 1;
    if (nc == 5) {  // flush chunks 0..4; stores drain under chunk 5's compute
      #pragma unroll
      for (int f = 0; f < 5; ++f) flush(f, pk[f]);
    }
    if (nc < 8) {  // prefetch next chunk into regs (hidden under MFMA)
      #pragma unroll
      for (int jj = 0; jj < 3; ++jj) {
        int j = tid + jj * 512;
        st[jj] = *(const uint4*)(WqkvT + (nc + 1) * 12288 + (j / 24) * 192 + (j % 24) * 8);
      }
    }
    f32x4 acc[4] = {z, z, z, z};
    #pragma unroll
    for (int ks = 0; ks < 6; ++ks) {
      const unsigned short* bp = &Bs[cur][c * 200 + ks * 32 + g * 8];
      #pragma unroll
      for (int nf = 0; nf < 4; ++nf)
        acc[nf] = MFMA(af[ks], *(const bf16x8*)(bp + nf * 16 * 200), acc[nf]);
    }
    // pack to bf16 regs (no LDS, no stores inside barrier region)
    const int slot = nc < 5 ? nc : nc - 5;
    #pragma unroll
    for (int nf = 0; nf < 4; ++nf) {
      const float bb = bqkv[nc * 64 + nf * 16 + c];
      u16x4 p;
      #pragma unroll
      for (int r = 0; r < 4; ++r) p[r] = f2bf(acc[nf][r] + bb);
      pk[slot][nf] = p;
    }
    if (nc < 8) {
      #pragma unroll
      for (int jj = 0; jj < 3; ++jj) {
        int j = tid + jj * 512;
        *(uint4*)(&Bs[cur ^ 1][(j / 24) * 200 + (j % 24) * 8]) = st[jj];
      }
    }
    __syncthreads();
  }
  // flush chunks 5..8 after the last barrier; stores drain at kernel end
  #pragma unroll
  for (int f = 0; f < 4; ++f) flush(5 + f, pk[f]);
}

// ---------------- K2: windowed attention ----------------
// grid 4096 (1 window), 512 threads. Wave (mt, hw): heads hw*3..hw*3+2.
// Reads Q/K/V from qkv; writes attn-out into qkv cols [0,192) (Q is dead).
__global__ __launch_bounds__(512, 4)
void attn_win(unsigned short* __restrict__ qkv, const float* __restrict__ btab) {
  __shared__ __align__(16) unsigned short Ks[64 * 200];   // K rows [tok][d192], padded
  __shared__ __align__(16) unsigned short Vt[192 * 72];   // V^T [d][tok]
  __shared__ __align__(16) unsigned short scr[8][1152];   // per-wave P / O bounce
  __shared__ float biasF[1014];

  const int tid = threadIdx.x, w8 = tid >> 6, lane = tid & 63;
  const int g = lane >> 4, c = lane & 15;
  const int mt = w8 & 3, hw = w8 >> 2;
  const size_t tokbase = (size_t)blockIdx.x * 49;
  const f32x4 z = {0.f, 0.f, 0.f, 0.f};

  for (int j = tid; j < 1014; j += 512) biasF[j] = btab[j];
  for (int j = tid; j < 360; j += 512) {      // zero K pad rows 49..63
    uint4 zz = {0, 0, 0, 0};
    *(uint4*)(&Ks[(49 + j / 24) * 200 + (j % 24) * 8]) = zz;
  }
  for (int j = tid; j < 2880; j += 512) Vt[(j / 15) * 72 + 49 + j % 15] = 0;  // V^T pad cols
  for (int j = tid; j < 1176; j += 512) {     // K rows: straight copy
    int row = j / 24, ch = j % 24;
    *(uint4*)(&Ks[row * 200 + ch * 8]) =
        *(const uint4*)(qkv + (tokbase + row) * 576 + 192 + ch * 8);
  }
  for (int j = tid; j < 1176; j += 512) {     // V: transpose-scatter -> Vt[d][tok]
    int row = j / 24, ch = j % 24;
    uint4 v = *(const uint4*)(qkv + (tokbase + row) * 576 + 384 + ch * 8);
    const unsigned short* e = (const unsigned short*)&v;
    #pragma unroll
    for (int m = 0; m < 8; ++m) {             // rotated order: 24-way -> 3-way conflicts
      int k = (ch + m) & 7;
      Vt[(ch * 8 + k) * 72 + row] = e[k];
    }
  }
  __syncthreads();  // the only barrier

  const int qbase = mt * 16;
  const int q = qbase + c;
  const bool qvalid = q < 49;
  const int qc = qvalid ? q : 48;
  const int qoff6 = ((6 - qc / 7) * 13 + (6 - qc % 7)) * 6;
  int kb6[16];
  #pragma unroll
  for (int i = 0; i < 16; ++i) {
    int k = (i >> 2) * 16 + g * 4 + (i & 3);
    int kk = k < 49 ? k : 48;
    kb6[i] = ((kk / 7) * 13 + (kk % 7)) * 6;
  }
  unsigned short* Pw = scr[w8];

  for (int hi = 0; hi < 3; ++hi) {
    const int h = hw * 3 + hi;
    const bf16x8 bq = *(const bf16x8*)(qkv + (tokbase + qc) * 576 + h * 32 + g * 8);
    const int cofs = h * 32 + g * 8;
    f32x4 s0 = MFMA(*(const bf16x8*)(Ks + (c) * 200 + cofs), bq, z);
    f32x4 s1 = MFMA(*(const bf16x8*)(Ks + (16 + c) * 200 + cofs), bq, z);
    f32x4 s2 = MFMA(*(const bf16x8*)(Ks + (32 + c) * 200 + cofs), bq, z);
    f32x4 s3 = MFMA(*(const bf16x8*)(Ks + (48 + c) * 200 + cofs), bq, z);

    // softmax: lane holds S^T[k=16t+4g+r][q=qbase+c]  (verified layout)
    float p[16];
    float mx = -3e38f;
    #pragma unroll
    for (int i = 0; i < 16; ++i) {
      const int t = i >> 2, r = i & 3;
      const int k = t * 16 + g * 4 + r;
      const float sv = (t == 0) ? s0[r] : (t == 1) ? s1[r] : (t == 2) ? s2[r] : s3[r];
      const float b = biasF[kb6[i] + qoff6 + h];
      const float lg = (qvalid && (k < 49)) ? fmaf(sv, SCALE, b) : -1e30f;
      p[i] = lg;
      mx = fmaxf(mx, lg);
    }
    mx = fmaxf(mx, __shfl_xor(mx, 16));
    mx = fmaxf(mx, __shfl_xor(mx, 32));
    float sum = 0.f;
    #pragma unroll
    for (int i = 0; i < 16; ++i) { p[i] = __expf(p[i] - mx); sum += p[i]; }
    sum += __shfl_xor(sum, 16);
    sum += __shfl_xor(sum, 32);
    const float inv = 1.0f / sum;
    #pragma unroll
    for (int t = 0; t < 4; ++t) {
      u16x4 pkv;
      #pragma unroll
      for (int r = 0; r < 4; ++r) pkv[r] = f2bf(p[t * 4 + r] * inv);
      *(u16x4*)(Pw + c * 72 + t * 16 + g * 4) = pkv;  // P[q-local=c][k]
    }

    // PV: A = P (wave-private), B = Vt[d][tok]
    f32x4 o0 = z, o1 = z;
    #pragma unroll
    for (int ks = 0; ks < 2; ++ks) {
      const bf16x8 ap = *(const bf16x8*)(Pw + c * 72 + ks * 32 + g * 8);
      const bf16x8 v0 = *(const bf16x8*)(Vt + (h * 32 + c) * 72 + ks * 32 + g * 8);
      const bf16x8 v1 = *(const bf16x8*)(Vt + (h * 32 + 16 + c) * 72 + ks * 32 + g * 8);
      o0 = MFMA(ap, v0, o0);
      o1 = MFMA(ap, v1, o1);
    }
    #pragma unroll
    for (int r = 0; r < 4; ++r) {
      Pw[(4 * g + r) * 72 + c]      = f2bf(o0[r]);
      Pw[(4 * g + r) * 72 + 16 + c] = f2bf(o1[r]);
    }
    uint4 ov = *(const uint4*)(Pw + c * 72 + g * 8);
    if (qvalid)
      *(uint4*)(qkv + (tokbase + q) * 576 + h * 32 + g * 8) = ov;
  }
}

// ---------------- K3: output projection, 128 rows/block (v5 version) ----------------
__global__ __launch_bounds__(512, 4)
void out_gemm(const unsigned short* __restrict__ qkv, const unsigned short* __restrict__ WoT,
              const float* __restrict__ bo, float* __restrict__ out) {
  __shared__ __align__(16) unsigned short Ws[192 * 200];  // 76.8 KB, padded

  const int tid = threadIdx.x, w8 = tid >> 6, lane = tid & 63;
  const int g = lane >> 4, c = lane & 15;
  const size_t bm = (size_t)blockIdx.x * 128;
  const f32x4 z = {0.f, 0.f, 0.f, 0.f};

  #pragma unroll
  for (int jj = 0; jj < 9; ++jj) {  // 192 rows x 24 chunks of 16B
    int j = tid + jj * 512;
    *(uint4*)(&Ws[(j / 24) * 200 + (j % 24) * 8]) = *(const uint4*)(WoT + (j / 24) * 192 + (j % 24) * 8);
  }
  __syncthreads();

  bf16x8 af[6];
  #pragma unroll
  for (int ks = 0; ks < 6; ++ks)
    af[ks] = *(const bf16x8*)(qkv + (bm + w8 * 16 + c) * 576 + ks * 32 + g * 8);

  #pragma unroll
  for (int nf = 0; nf < 12; ++nf) {
    const int col = nf * 16 + c;
    const unsigned short* bp = Ws + col * 200;
    f32x4 acc = z;
    #pragma unroll
    for (int ks = 0; ks < 6; ++ks)
      acc = MFMA(af[ks], *(const bf16x8*)(bp + ks * 32 + g * 8), acc);
    const float bb = bo[col];
    #pragma unroll
    for (int r = 0; r < 4; ++r)
      out[(bm + w8 * 16 + 4 * g + r) * 192 + col] = acc[r] + bb;
  }
}

extern "C" void kernel_launch(void* const* d_in, const int* in_sizes, int n_in,
                              void* d_out, int out_size, void* d_ws, size_t ws_size,
                              hipStream_t stream) {
  (void)in_sizes; (void)n_in; (void)out_size; (void)ws_size;
  const float* X    = (const float*)d_in[0];
  const float* Wqkv = (const float*)d_in[1];
  const float* bqkv = (const float*)d_in[2];
  const float* Wo   = (const float*)d_in[3];
  const float* bo   = (const float*)d_in[4];
  const float* btab = (const float*)d_in[5];

  unsigned short* WqkvT = (unsigned short*)d_ws;   // 576*192 bf16
  unsigned short* WoT   = WqkvT + 576 * 192;       // 192*192 bf16
  unsigned short* qkv   = WoT + 192 * 192;         // 200704*576 bf16 (231 MB)

  wprep<<<432, 256, 0, stream>>>(Wqkv, Wo, WqkvT, WoT);
  qkv_gemm<<<1568, 512, 0, stream>>>(X, WqkvT, bqkv, qkv);
  attn_win<<<4096, 512, 0, stream>>>(qkv, btab);
  out_gemm<<<1568, 512, 0, stream>>>(qkv, WoT, bo, (float*)d_out);
}

// Round 8
// 322.477 us; speedup vs baseline: 1.0641x; 1.0641x over previous
//
#include <hip/hip_runtime.h>
#include <hip/hip_bf16.h>

// WinMSA for MI355X (gfx950), v8: 2-kernel pipeline through d_ws.
//   K1: qkv = X @ Wqkv + b   (v5 shape; weight staging via async global_load_lds
//       with pre-swizzled source -> linear LDS dest + bank-balanced swizzled reads)
//   K2: fused attention + out-projection per window (attn-out never touches HBM;
//       Wo staged in 2 chunks overlaying dead K/V LDS regions)

typedef __attribute__((ext_vector_type(4))) float f32x4;
typedef __attribute__((ext_vector_type(8))) short bf16x8;
typedef __attribute__((ext_vector_type(4))) unsigned short u16x4;

#define SCALE 0.17677669529663689f  // 32^-0.5
#define MFMA(a, b, acc) __builtin_amdgcn_mfma_f32_16x16x32_bf16(a, b, acc, 0, 0, 0)

__device__ __forceinline__ unsigned short f2bf(float f) {
  union { float f; unsigned int u; } v; v.f = f;
  return (unsigned short)((v.u + 0x7FFFu + ((v.u >> 16) & 1u)) >> 16);  // RNE
}

// async global->LDS, 16B per lane; LDS dest is wave-uniform base + lane*16
__device__ __forceinline__ void gll16(const unsigned short* src, unsigned short* dst) {
  __builtin_amdgcn_global_load_lds(
      (const __attribute__((address_space(1))) unsigned int*)src,
      (__attribute__((address_space(3))) unsigned int*)dst, 16, 0, 0);
}

// Pre-kernel: Wqkv -> bf16 [chunk][row=outcol%64][k] with 16B-block XOR swizzle
// (blk ^= row&7) so K1's linear global_load_lds staging yields bank-balanced reads.
// Wo -> plain bf16 [out][in].
__global__ void wprep(const float* __restrict__ Wqkv, const float* __restrict__ Wo,
                      unsigned short* __restrict__ WqkvTs, unsigned short* __restrict__ WoT) {
  int i = blockIdx.x * 256 + threadIdx.x;
  if (i < 576 * 192) {
    int n = i / 192, k = i % 192;
    int ch = n >> 6, row = n & 63;
    int dst = ch * 12288 + row * 192 + (((k >> 3) ^ (row & 7)) << 3) + (k & 7);
    WqkvTs[dst] = f2bf(Wqkv[k * 576 + n]);
  }
  if (i < 192 * 192) { int n = i / 192, k = i % 192; WoT[i] = f2bf(Wo[k * 192 + n]); }
}

// ---------------- K1: qkv GEMM, 128 rows/block, async-LDS weight staging ----------------
__global__ __launch_bounds__(512, 4)
void qkv_gemm(const float* __restrict__ X, const unsigned short* __restrict__ WqkvTs,
              const float* __restrict__ bqkv, unsigned short* __restrict__ qkv) {
  __shared__ __align__(16) unsigned short Bs[2][12288];  // weight chunk dbuf, UNPADDED (swizzled)
  __shared__ __align__(16) unsigned short scr[8][1152];  // per-wave store bounce

  const int tid = threadIdx.x, w8 = tid >> 6, lane = tid & 63;
  const int g = lane >> 4, c = lane & 15;
  const size_t bm = (size_t)blockIdx.x * 128;
  const f32x4 z = {0.f, 0.f, 0.f, 0.f};

  // A-fragments: 16 rows of X per wave, f32 -> bf16, register-resident
  bf16x8 af[6];
  {
    const float* xr = X + (bm + w8 * 16 + c) * 192;
    #pragma unroll
    for (int ks = 0; ks < 6; ++ks) {
      f32x4 lo = *(const f32x4*)(xr + ks * 32 + g * 8);
      f32x4 hi = *(const f32x4*)(xr + ks * 32 + g * 8 + 4);
      bf16x8 a;
      a[0] = (short)f2bf(lo[0]); a[1] = (short)f2bf(lo[1]);
      a[2] = (short)f2bf(lo[2]); a[3] = (short)f2bf(lo[3]);
      a[4] = (short)f2bf(hi[0]); a[5] = (short)f2bf(hi[1]);
      a[6] = (short)f2bf(hi[2]); a[7] = (short)f2bf(hi[3]);
      af[ks] = a;
    }
  }

  // stage chunk 0 (async direct to LDS)
  #pragma unroll
  for (int jj = 0; jj < 3; ++jj)
    gll16(WqkvTs + (w8 * 3 + jj) * 512 + lane * 8, &Bs[0][(w8 * 3 + jj) * 512]);
  __syncthreads();

  unsigned short* sw = scr[w8];
  for (int nc = 0; nc < 9; ++nc) {
    const int cur = nc & 1;
    if (nc < 8) {  // async-stage next chunk; drains under this chunk's compute
      #pragma unroll
      for (int jj = 0; jj < 3; ++jj)
        gll16(WqkvTs + (nc + 1) * 12288 + (w8 * 3 + jj) * 512 + lane * 8,
              &Bs[cur ^ 1][(w8 * 3 + jj) * 512]);
    }
    f32x4 acc[4] = {z, z, z, z};
    #pragma unroll
    for (int ks = 0; ks < 6; ++ks) {
      #pragma unroll
      for (int nf = 0; nf < 4; ++nf) {
        const bf16x8 bv = *(const bf16x8*)(
            &Bs[cur][(nf * 16 + c) * 192 + (((ks * 4 + g) ^ (c & 7)) << 3)]);
        acc[nf] = MFMA(af[ks], bv, acc[nf]);
      }
    }
    // bias + bounce (tile rows 4g+r, col c) -> coalesced 16B stores, spread per chunk
    #pragma unroll
    for (int nf = 0; nf < 4; ++nf) {
      const float bb = bqkv[nc * 64 + nf * 16 + c];
      #pragma unroll
      for (int r = 0; r < 4; ++r)
        sw[(4 * g + r) * 72 + nf * 16 + c] = f2bf(acc[nf][r] + bb);
    }
    uint4 o0 = *(const uint4*)(sw + c * 72 + g * 8);
    uint4 o1 = *(const uint4*)(sw + c * 72 + 32 + g * 8);
    unsigned short* qp = qkv + (bm + w8 * 16 + c) * 576 + nc * 64;
    *(uint4*)(qp + g * 8)      = o0;
    *(uint4*)(qp + 32 + g * 8) = o1;
    __syncthreads();
  }
}

// ---------------- K2: fused windowed attention + output projection ----------------
// grid 4096 (1 window), 512 threads, 8 waves = (mt 0..3, hw 0..1), 5 barriers.
// Phase 1: attention (AO kept in registers). Phase 2: AO -> LDS (over Ks),
// Wo chunks staged over Vt/scr, out-proj, fp32 stores.
__global__ __launch_bounds__(512, 4)
void attn_out(const unsigned short* __restrict__ qkv, const float* __restrict__ btab,
              const unsigned short* __restrict__ WoT, const float* __restrict__ bo,
              float* __restrict__ out) {
  __shared__ __align__(16) unsigned char smem[75776];
  unsigned short* Ks  = (unsigned short*)smem;             // [64][200]   phase 1
  unsigned short* Vt  = (unsigned short*)(smem + 25600);   // [192][72]   phase 1
  unsigned short* scr = (unsigned short*)(smem + 53248);   // 8 x [16*72] phase 1
  float* biasF        = (float*)(smem + 71680);            // [1014]      phase 1
  unsigned short* AOs = (unsigned short*)smem;             // [64][200]   phase 2
  unsigned short* Wos = (unsigned short*)(smem + 25600);   // [96][200]   phase 2

  const int tid = threadIdx.x, w8 = tid >> 6, lane = tid & 63;
  const int g = lane >> 4, c = lane & 15;
  const int mt = w8 & 3, hw = w8 >> 2;
  const int wb = blockIdx.x;
  const size_t tokbase = (size_t)wb * 49;
  const f32x4 z = {0.f, 0.f, 0.f, 0.f};

  for (int j = tid; j < 1014; j += 512) biasF[j] = btab[j];
  for (int j = tid; j < 360; j += 512) {      // zero K pad rows 49..63
    uint4 zz = {0, 0, 0, 0};
    *(uint4*)(&Ks[(49 + j / 24) * 200 + (j % 24) * 8]) = zz;
  }
  for (int j = tid; j < 2880; j += 512) Vt[(j / 15) * 72 + 49 + j % 15] = 0;  // V^T pad cols
  for (int j = tid; j < 1176; j += 512) {     // K rows: straight copy
    int row = j / 24, ch = j % 24;
    *(uint4*)(&Ks[row * 200 + ch * 8]) =
        *(const uint4*)(qkv + (tokbase + row) * 576 + 192 + ch * 8);
  }
  for (int j = tid; j < 1176; j += 512) {     // V: transpose-scatter, rotated (3-way)
    int row = j / 24, ch = j % 24;
    uint4 v = *(const uint4*)(qkv + (tokbase + row) * 576 + 384 + ch * 8);
    const unsigned short* e = (const unsigned short*)&v;
    #pragma unroll
    for (int m = 0; m < 8; ++m) {
      int k = (ch + m) & 7;
      Vt[(ch * 8 + k) * 72 + row] = e[k];
    }
  }
  __syncthreads();  // B1: K/V/bias staged

  const int qbase = mt * 16;
  const int q = qbase + c;
  const bool qvalid = q < 49;
  const int qc = qvalid ? q : 48;
  const int qoff6 = ((6 - qc / 7) * 13 + (6 - qc % 7)) * 6;
  int kb6[16];
  #pragma unroll
  for (int i = 0; i < 16; ++i) {
    int k = (i >> 2) * 16 + g * 4 + (i & 3);
    int kk = k < 49 ? k : 48;
    kb6[i] = ((kk / 7) * 13 + (kk % 7)) * 6;
  }
  unsigned short* Pw = scr + w8 * 1152;
  u16x4 pk0[3], pk1[3];  // attn-out, packed bf16 (rows 4g+r, cols h*32+{c,16+c})

  #pragma unroll
  for (int hi = 0; hi < 3; ++hi) {
    const int h = hw * 3 + hi;
    const bf16x8 bq = *(const bf16x8*)(qkv + (tokbase + qc) * 576 + h * 32 + g * 8);
    const int cofs = h * 32 + g * 8;
    f32x4 s0 = MFMA(*(const bf16x8*)(Ks + (c) * 200 + cofs), bq, z);
    f32x4 s1 = MFMA(*(const bf16x8*)(Ks + (16 + c) * 200 + cofs), bq, z);
    f32x4 s2 = MFMA(*(const bf16x8*)(Ks + (32 + c) * 200 + cofs), bq, z);
    f32x4 s3 = MFMA(*(const bf16x8*)(Ks + (48 + c) * 200 + cofs), bq, z);

    // softmax: lane holds S^T[k=16t+4g+r][q=qbase+c]  (verified layout)
    float p[16];
    float mx = -3e38f;
    #pragma unroll
    for (int i = 0; i < 16; ++i) {
      const int t = i >> 2, r = i & 3;
      const int k = t * 16 + g * 4 + r;
      const float sv = (t == 0) ? s0[r] : (t == 1) ? s1[r] : (t == 2) ? s2[r] : s3[r];
      const float b = biasF[kb6[i] + qoff6 + h];
      const float lg = (qvalid && (k < 49)) ? fmaf(sv, SCALE, b) : -1e30f;
      p[i] = lg;
      mx = fmaxf(mx, lg);
    }
    mx = fmaxf(mx, __shfl_xor(mx, 16));
    mx = fmaxf(mx, __shfl_xor(mx, 32));
    float sum = 0.f;
    #pragma unroll
    for (int i = 0; i < 16; ++i) { p[i] = __expf(p[i] - mx); sum += p[i]; }
    sum += __shfl_xor(sum, 16);
    sum += __shfl_xor(sum, 32);
    const float inv = 1.0f / sum;
    #pragma unroll
    for (int t = 0; t < 4; ++t) {
      u16x4 pkv;
      #pragma unroll
      for (int r = 0; r < 4; ++r) pkv[r] = f2bf(p[t * 4 + r] * inv);
      *(u16x4*)(Pw + c * 72 + t * 16 + g * 4) = pkv;  // P[q-local=c][k]
    }

    // PV: A = P (wave-private), B = Vt[d][tok]; result stays in registers
    f32x4 o0 = z, o1 = z;
    #pragma unroll
    for (int ks = 0; ks < 2; ++ks) {
      const bf16x8 ap = *(const bf16x8*)(Pw + c * 72 + ks * 32 + g * 8);
      const bf16x8 v0 = *(const bf16x8*)(Vt + (h * 32 + c) * 72 + ks * 32 + g * 8);
      const bf16x8 v1 = *(const bf16x8*)(Vt + (h * 32 + 16 + c) * 72 + ks * 32 + g * 8);
      o0 = MFMA(ap, v0, o0);
      o1 = MFMA(ap, v1, o1);
    }
    #pragma unroll
    for (int r = 0; r < 4; ++r) { pk0[hi][r] = f2bf(o0[r]); pk1[hi][r] = f2bf(o1[r]); }
  }
  __syncthreads();  // B2: attention done; Ks/Vt/scr dead

  // AO -> LDS (over Ks region) + stage Wo chunk 0 (over Vt/scr region)
  #pragma unroll
  for (int hi = 0; hi < 3; ++hi) {
    const int h = hw * 3 + hi;
    #pragma unroll
    for (int r = 0; r < 4; ++r) {
      AOs[(mt * 16 + 4 * g + r) * 200 + h * 32 + c]      = pk0[hi][r];
      AOs[(mt * 16 + 4 * g + r) * 200 + h * 32 + 16 + c] = pk1[hi][r];
    }
  }
  for (int j = tid; j < 2304; j += 512)
    *(uint4*)(&Wos[(j / 24) * 200 + (j % 24) * 8]) =
        *(const uint4*)(WoT + (j / 24) * 192 + (j % 24) * 8);
  __syncthreads();  // B3: AO + Wo chunk 0 ready

  bf16x8 af2[6];
  #pragma unroll
  for (int ks = 0; ks < 6; ++ks)
    af2[ks] = *(const bf16x8*)(AOs + (mt * 16 + c) * 200 + ks * 32 + g * 8);
  float* og = out + (size_t)wb * 9408;

  #pragma unroll
  for (int ct = 0; ct < 3; ++ct) {  // out cols 0..95
    const int col = hw * 48 + ct * 16 + c;
    const unsigned short* bp = Wos + col * 200;
    f32x4 acc = z;
    #pragma unroll
    for (int ks = 0; ks < 6; ++ks)
      acc = MFMA(af2[ks], *(const bf16x8*)(bp + ks * 32 + g * 8), acc);
    const float bb = bo[col];
    #pragma unroll
    for (int r = 0; r < 4; ++r) {
      const int row = mt * 16 + 4 * g + r;
      if (row < 49) og[row * 192 + col] = acc[r] + bb;
    }
  }
  __syncthreads();  // B4: chunk 0 reads done
  for (int j = tid; j < 2304; j += 512)
    *(uint4*)(&Wos[(j / 24) * 200 + (j % 24) * 8]) =
        *(const uint4*)(WoT + (96 + j / 24) * 192 + (j % 24) * 8);
  __syncthreads();  // B5: Wo chunk 1 ready

  #pragma unroll
  for (int ct = 0; ct < 3; ++ct) {  // out cols 96..191
    const int col = 96 + hw * 48 + ct * 16 + c;
    const unsigned short* bp = Wos + (col - 96) * 200;
    f32x4 acc = z;
    #pragma unroll
    for (int ks = 0; ks < 6; ++ks)
      acc = MFMA(af2[ks], *(const bf16x8*)(bp + ks * 32 + g * 8), acc);
    const float bb = bo[col];
    #pragma unroll
    for (int r = 0; r < 4; ++r) {
      const int row = mt * 16 + 4 * g + r;
      if (row < 49) og[row * 192 + col] = acc[r] + bb;
    }
  }
}

extern "C" void kernel_launch(void* const* d_in, const int* in_sizes, int n_in,
                              void* d_out, int out_size, void* d_ws, size_t ws_size,
                              hipStream_t stream) {
  (void)in_sizes; (void)n_in; (void)out_size; (void)ws_size;
  const float* X    = (const float*)d_in[0];
  const float* Wqkv = (const float*)d_in[1];
  const float* bqkv = (const float*)d_in[2];
  const float* Wo   = (const float*)d_in[3];
  const float* bo   = (const float*)d_in[4];
  const float* btab = (const float*)d_in[5];

  unsigned short* WqkvTs = (unsigned short*)d_ws;  // 576*192 bf16 (swizzled layout)
  unsigned short* WoT    = WqkvTs + 576 * 192;     // 192*192 bf16
  unsigned short* qkv    = WoT + 192 * 192;        // 200704*576 bf16 (231 MB)

  wprep<<<432, 256, 0, stream>>>(Wqkv, Wo, WqkvTs, WoT);
  qkv_gemm<<<1568, 512, 0, stream>>>(X, WqkvTs, bqkv, qkv);
  attn_out<<<4096, 512, 0, stream>>>(qkv, btab, WoT, bo, (float*)d_out);
}

// Round 9
// 291.518 us; speedup vs baseline: 1.1772x; 1.1062x over previous
//
#include <hip/hip_runtime.h>
#include <hip/hip_bf16.h>

// WinMSA for MI355X (gfx950), v9: 3-kernel pipeline through d_ws.
//   K1: qkv = X @ Wqkv + b   (async global_load_lds staging of pre-swizzled weights)
//   K2: per-window attention (K/V LDS-staged, AO -> dead Q cols of qkv)
//   K3: out = AO @ Wo + bo   (NEW: same gll staging recipe as K1, unpadded+swizzled)

typedef __attribute__((ext_vector_type(4))) float f32x4;
typedef __attribute__((ext_vector_type(8))) short bf16x8;
typedef __attribute__((ext_vector_type(4))) unsigned short u16x4;

#define SCALE 0.17677669529663689f  // 32^-0.5
#define MFMA(a, b, acc) __builtin_amdgcn_mfma_f32_16x16x32_bf16(a, b, acc, 0, 0, 0)

__device__ __forceinline__ unsigned short f2bf(float f) {
  union { float f; unsigned int u; } v; v.f = f;
  return (unsigned short)((v.u + 0x7FFFu + ((v.u >> 16) & 1u)) >> 16);  // RNE
}

// async global->LDS, 16B per lane; LDS dest is wave-uniform base + lane*16
__device__ __forceinline__ void gll16(const unsigned short* src, unsigned short* dst) {
  __builtin_amdgcn_global_load_lds(
      (const __attribute__((address_space(1))) unsigned int*)src,
      (__attribute__((address_space(3))) unsigned int*)dst, 16, 0, 0);
}

// Pre-kernel: weights -> bf16 [out][in] with 16B-block XOR swizzle (blk ^= row&7)
// so linear global_load_lds staging yields bank-balanced swizzled ds_read_b128.
__global__ void wprep(const float* __restrict__ Wqkv, const float* __restrict__ Wo,
                      unsigned short* __restrict__ WqkvTs, unsigned short* __restrict__ WoTs) {
  int i = blockIdx.x * 256 + threadIdx.x;
  if (i < 576 * 192) {
    int n = i / 192, k = i % 192;
    int ch = n >> 6, row = n & 63;
    int dst = ch * 12288 + row * 192 + (((k >> 3) ^ (row & 7)) << 3) + (k & 7);
    WqkvTs[dst] = f2bf(Wqkv[k * 576 + n]);
  }
  if (i < 192 * 192) {
    int n = i / 192, k = i % 192;
    int dst = n * 192 + (((k >> 3) ^ (n & 7)) << 3) + (k & 7);
    WoTs[dst] = f2bf(Wo[k * 192 + n]);
  }
}

// ---------------- K1: qkv GEMM, 128 rows/block, async-LDS weight staging ----------------
__global__ __launch_bounds__(512, 4)
void qkv_gemm(const float* __restrict__ X, const unsigned short* __restrict__ WqkvTs,
              const float* __restrict__ bqkv, unsigned short* __restrict__ qkv) {
  __shared__ __align__(16) unsigned short Bs[2][12288];  // weight chunk dbuf, UNPADDED (swizzled)
  __shared__ __align__(16) unsigned short scr[8][1152];  // per-wave store bounce

  const int tid = threadIdx.x, w8 = tid >> 6, lane = tid & 63;
  const int g = lane >> 4, c = lane & 15;
  const size_t bm = (size_t)blockIdx.x * 128;
  const f32x4 z = {0.f, 0.f, 0.f, 0.f};

  // A-fragments: 16 rows of X per wave, f32 -> bf16, register-resident
  bf16x8 af[6];
  {
    const float* xr = X + (bm + w8 * 16 + c) * 192;
    #pragma unroll
    for (int ks = 0; ks < 6; ++ks) {
      f32x4 lo = *(const f32x4*)(xr + ks * 32 + g * 8);
      f32x4 hi = *(const f32x4*)(xr + ks * 32 + g * 8 + 4);
      bf16x8 a;
      a[0] = (short)f2bf(lo[0]); a[1] = (short)f2bf(lo[1]);
      a[2] = (short)f2bf(lo[2]); a[3] = (short)f2bf(lo[3]);
      a[4] = (short)f2bf(hi[0]); a[5] = (short)f2bf(hi[1]);
      a[6] = (short)f2bf(hi[2]); a[7] = (short)f2bf(hi[3]);
      af[ks] = a;
    }
  }

  // stage chunk 0 (async direct to LDS)
  #pragma unroll
  for (int jj = 0; jj < 3; ++jj)
    gll16(WqkvTs + (w8 * 3 + jj) * 512 + lane * 8, &Bs[0][(w8 * 3 + jj) * 512]);
  __syncthreads();

  unsigned short* sw = scr[w8];
  for (int nc = 0; nc < 9; ++nc) {
    const int cur = nc & 1;
    if (nc < 8) {  // async-stage next chunk; drains under this chunk's compute
      #pragma unroll
      for (int jj = 0; jj < 3; ++jj)
        gll16(WqkvTs + (nc + 1) * 12288 + (w8 * 3 + jj) * 512 + lane * 8,
              &Bs[cur ^ 1][(w8 * 3 + jj) * 512]);
    }
    f32x4 acc[4] = {z, z, z, z};
    #pragma unroll
    for (int ks = 0; ks < 6; ++ks) {
      #pragma unroll
      for (int nf = 0; nf < 4; ++nf) {
        const bf16x8 bv = *(const bf16x8*)(
            &Bs[cur][(nf * 16 + c) * 192 + (((ks * 4 + g) ^ (c & 7)) << 3)]);
        acc[nf] = MFMA(af[ks], bv, acc[nf]);
      }
    }
    // bias + bounce (tile rows 4g+r, col c) -> coalesced 16B stores, spread per chunk
    #pragma unroll
    for (int nf = 0; nf < 4; ++nf) {
      const float bb = bqkv[nc * 64 + nf * 16 + c];
      #pragma unroll
      for (int r = 0; r < 4; ++r)
        sw[(4 * g + r) * 72 + nf * 16 + c] = f2bf(acc[nf][r] + bb);
    }
    uint4 o0 = *(const uint4*)(sw + c * 72 + g * 8);
    uint4 o1 = *(const uint4*)(sw + c * 72 + 32 + g * 8);
    unsigned short* qp = qkv + (bm + w8 * 16 + c) * 576 + nc * 64;
    *(uint4*)(qp + g * 8)      = o0;
    *(uint4*)(qp + 32 + g * 8) = o1;
    __syncthreads();
  }
}

// ---------------- K2: windowed attention ----------------
// grid 4096 (1 window), 512 threads. Wave (mt, hw): heads hw*3..hw*3+2.
// Reads Q/K/V from qkv; writes attn-out into qkv cols [0,192) (Q is dead).
__global__ __launch_bounds__(512, 4)
void attn_win(unsigned short* __restrict__ qkv, const float* __restrict__ btab) {
  __shared__ __align__(16) unsigned short Ks[64 * 200];   // K rows [tok][d192], padded
  __shared__ __align__(16) unsigned short Vt[192 * 72];   // V^T [d][tok]
  __shared__ __align__(16) unsigned short scr[8][1152];   // per-wave P / O bounce
  __shared__ float biasF[1014];

  const int tid = threadIdx.x, w8 = tid >> 6, lane = tid & 63;
  const int g = lane >> 4, c = lane & 15;
  const int mt = w8 & 3, hw = w8 >> 2;
  const size_t tokbase = (size_t)blockIdx.x * 49;
  const f32x4 z = {0.f, 0.f, 0.f, 0.f};

  for (int j = tid; j < 1014; j += 512) biasF[j] = btab[j];
  for (int j = tid; j < 360; j += 512) {      // zero K pad rows 49..63
    uint4 zz = {0, 0, 0, 0};
    *(uint4*)(&Ks[(49 + j / 24) * 200 + (j % 24) * 8]) = zz;
  }
  for (int j = tid; j < 2880; j += 512) Vt[(j / 15) * 72 + 49 + j % 15] = 0;  // V^T pad cols
  for (int j = tid; j < 1176; j += 512) {     // K rows: straight copy
    int row = j / 24, ch = j % 24;
    *(uint4*)(&Ks[row * 200 + ch * 8]) =
        *(const uint4*)(qkv + (tokbase + row) * 576 + 192 + ch * 8);
  }
  for (int j = tid; j < 1176; j += 512) {     // V: transpose-scatter, rotated (3-way)
    int row = j / 24, ch = j % 24;
    uint4 v = *(const uint4*)(qkv + (tokbase + row) * 576 + 384 + ch * 8);
    const unsigned short* e = (const unsigned short*)&v;
    #pragma unroll
    for (int m = 0; m < 8; ++m) {
      int k = (ch + m) & 7;
      Vt[(ch * 8 + k) * 72 + row] = e[k];
    }
  }
  __syncthreads();  // the only barrier

  const int qbase = mt * 16;
  const int q = qbase + c;
  const bool qvalid = q < 49;
  const int qc = qvalid ? q : 48;
  const int qoff6 = ((6 - qc / 7) * 13 + (6 - qc % 7)) * 6;
  int kb6[16];
  #pragma unroll
  for (int i = 0; i < 16; ++i) {
    int k = (i >> 2) * 16 + g * 4 + (i & 3);
    int kk = k < 49 ? k : 48;
    kb6[i] = ((kk / 7) * 13 + (kk % 7)) * 6;
  }
  unsigned short* Pw = scr[w8];

  for (int hi = 0; hi < 3; ++hi) {
    const int h = hw * 3 + hi;
    const bf16x8 bq = *(const bf16x8*)(qkv + (tokbase + qc) * 576 + h * 32 + g * 8);
    const int cofs = h * 32 + g * 8;
    f32x4 s0 = MFMA(*(const bf16x8*)(Ks + (c) * 200 + cofs), bq, z);
    f32x4 s1 = MFMA(*(const bf16x8*)(Ks + (16 + c) * 200 + cofs), bq, z);
    f32x4 s2 = MFMA(*(const bf16x8*)(Ks + (32 + c) * 200 + cofs), bq, z);
    f32x4 s3 = MFMA(*(const bf16x8*)(Ks + (48 + c) * 200 + cofs), bq, z);

    // softmax: lane holds S^T[k=16t+4g+r][q=qbase+c]  (verified layout)
    float p[16];
    float mx = -3e38f;
    #pragma unroll
    for (int i = 0; i < 16; ++i) {
      const int t = i >> 2, r = i & 3;
      const int k = t * 16 + g * 4 + r;
      const float sv = (t == 0) ? s0[r] : (t == 1) ? s1[r] : (t == 2) ? s2[r] : s3[r];
      const float b = biasF[kb6[i] + qoff6 + h];
      const float lg = (qvalid && (k < 49)) ? fmaf(sv, SCALE, b) : -1e30f;
      p[i] = lg;
      mx = fmaxf(mx, lg);
    }
    mx = fmaxf(mx, __shfl_xor(mx, 16));
    mx = fmaxf(mx, __shfl_xor(mx, 32));
    float sum = 0.f;
    #pragma unroll
    for (int i = 0; i < 16; ++i) { p[i] = __expf(p[i] - mx); sum += p[i]; }
    sum += __shfl_xor(sum, 16);
    sum += __shfl_xor(sum, 32);
    const float inv = 1.0f / sum;
    #pragma unroll
    for (int t = 0; t < 4; ++t) {
      u16x4 pkv;
      #pragma unroll
      for (int r = 0; r < 4; ++r) pkv[r] = f2bf(p[t * 4 + r] * inv);
      *(u16x4*)(Pw + c * 72 + t * 16 + g * 4) = pkv;  // P[q-local=c][k]
    }

    // PV: A = P (wave-private), B = Vt[d][tok]
    f32x4 o0 = z, o1 = z;
    #pragma unroll
    for (int ks = 0; ks < 2; ++ks) {
      const bf16x8 ap = *(const bf16x8*)(Pw + c * 72 + ks * 32 + g * 8);
      const bf16x8 v0 = *(const bf16x8*)(Vt + (h * 32 + c) * 72 + ks * 32 + g * 8);
      const bf16x8 v1 = *(const bf16x8*)(Vt + (h * 32 + 16 + c) * 72 + ks * 32 + g * 8);
      o0 = MFMA(ap, v0, o0);
      o1 = MFMA(ap, v1, o1);
    }
    #pragma unroll
    for (int r = 0; r < 4; ++r) {
      Pw[(4 * g + r) * 72 + c]      = f2bf(o0[r]);
      Pw[(4 * g + r) * 72 + 16 + c] = f2bf(o1[r]);
    }
    uint4 ov = *(const uint4*)(Pw + c * 72 + g * 8);
    if (qvalid)
      *(uint4*)(qkv + (tokbase + q) * 576 + h * 32 + g * 8) = ov;
  }
}

// ---------------- K3: output projection, 128 rows/block, async-LDS Wo staging ----------------
__global__ __launch_bounds__(512, 4)
void out_gemm(const unsigned short* __restrict__ qkv, const unsigned short* __restrict__ WoTs,
              const float* __restrict__ bo, float* __restrict__ out) {
  __shared__ __align__(16) unsigned short Ws[192 * 192];  // 73.7 KB, UNPADDED (swizzled)

  const int tid = threadIdx.x, w8 = tid >> 6, lane = tid & 63;
  const int g = lane >> 4, c = lane & 15;
  const size_t bm = (size_t)blockIdx.x * 128;
  const f32x4 z = {0.f, 0.f, 0.f, 0.f};

  // stage all of Wo async: 72 wave-chunks of 1 KB, linear LDS dest
  #pragma unroll
  for (int jj = 0; jj < 9; ++jj)
    gll16(WoTs + (w8 * 9 + jj) * 512 + lane * 8, &Ws[(w8 * 9 + jj) * 512]);

  // A-fragments while the staging flies
  bf16x8 af[6];
  #pragma unroll
  for (int ks = 0; ks < 6; ++ks)
    af[ks] = *(const bf16x8*)(qkv + (bm + w8 * 16 + c) * 576 + ks * 32 + g * 8);
  __syncthreads();  // drains vmcnt (gll) before reads

  #pragma unroll
  for (int nf = 0; nf < 12; ++nf) {
    const int col = nf * 16 + c;
    f32x4 acc = z;
    #pragma unroll
    for (int ks = 0; ks < 6; ++ks) {
      const bf16x8 bv = *(const bf16x8*)(
          &Ws[col * 192 + (((ks * 4 + g) ^ (c & 7)) << 3)]);
      acc = MFMA(af[ks], bv, acc);
    }
    const float bb = bo[col];
    #pragma unroll
    for (int r = 0; r < 4; ++r)
      out[(bm + w8 * 16 + 4 * g + r) * 192 + col] = acc[r] + bb;
  }
}

extern "C" void kernel_launch(void* const* d_in, const int* in_sizes, int n_in,
                              void* d_out, int out_size, void* d_ws, size_t ws_size,
                              hipStream_t stream) {
  (void)in_sizes; (void)n_in; (void)out_size; (void)ws_size;
  const float* X    = (const float*)d_in[0];
  const float* Wqkv = (const float*)d_in[1];
  const float* bqkv = (const float*)d_in[2];
  const float* Wo   = (const float*)d_in[3];
  const float* bo   = (const float*)d_in[4];
  const float* btab = (const float*)d_in[5];

  unsigned short* WqkvTs = (unsigned short*)d_ws;  // 576*192 bf16 (swizzled layout)
  unsigned short* WoTs   = WqkvTs + 576 * 192;     // 192*192 bf16 (swizzled layout)
  unsigned short* qkv    = WoTs + 192 * 192;       // 200704*576 bf16 (231 MB)

  wprep<<<432, 256, 0, stream>>>(Wqkv, Wo, WqkvTs, WoTs);
  qkv_gemm<<<1568, 512, 0, stream>>>(X, WqkvTs, bqkv, qkv);
  attn_win<<<4096, 512, 0, stream>>>(qkv, btab);
  out_gemm<<<1568, 512, 0, stream>>>(qkv, WoTs, bo, (float*)d_out);
}

// Round 10
// 281.387 us; speedup vs baseline: 1.2195x; 1.0360x over previous
//
#include <hip/hip_runtime.h>
#include <hip/hip_bf16.h>

// WinMSA for MI355X (gfx950), v10: 3-kernel pipeline through d_ws.
//   K1: qkv = X @ Wqkv + b   (gll staging; NEW: bias via LDS + counted-vmcnt raw
//       barriers -> stores stay in flight across barriers, no mid-chunk drains)
//   K2: per-window attention (NEW: Q loads hoisted out of the aliased head loop)
//   K3: out = AO @ Wo + bo   (unchanged from v9)

typedef __attribute__((ext_vector_type(4))) float f32x4;
typedef __attribute__((ext_vector_type(8))) short bf16x8;
typedef __attribute__((ext_vector_type(4))) unsigned short u16x4;

#define SCALE 0.17677669529663689f  // 32^-0.5
#define MFMA(a, b, acc) __builtin_amdgcn_mfma_f32_16x16x32_bf16(a, b, acc, 0, 0, 0)

__device__ __forceinline__ unsigned short f2bf(float f) {
  union { float f; unsigned int u; } v; v.f = f;
  return (unsigned short)((v.u + 0x7FFFu + ((v.u >> 16) & 1u)) >> 16);  // RNE
}

// async global->LDS, 16B per lane; LDS dest is wave-uniform base + lane*16
__device__ __forceinline__ void gll16(const unsigned short* src, unsigned short* dst) {
  __builtin_amdgcn_global_load_lds(
      (const __attribute__((address_space(1))) unsigned int*)src,
      (__attribute__((address_space(3))) unsigned int*)dst, 16, 0, 0);
}

// Pre-kernel: weights -> bf16 [out][in] with 16B-block XOR swizzle (blk ^= row&7)
// so linear global_load_lds staging yields bank-balanced swizzled ds_read_b128.
__global__ void wprep(const float* __restrict__ Wqkv, const float* __restrict__ Wo,
                      unsigned short* __restrict__ WqkvTs, unsigned short* __restrict__ WoTs) {
  int i = blockIdx.x * 256 + threadIdx.x;
  if (i < 576 * 192) {
    int n = i / 192, k = i % 192;
    int ch = n >> 6, row = n & 63;
    int dst = ch * 12288 + row * 192 + (((k >> 3) ^ (row & 7)) << 3) + (k & 7);
    WqkvTs[dst] = f2bf(Wqkv[k * 576 + n]);
  }
  if (i < 192 * 192) {
    int n = i / 192, k = i % 192;
    int dst = n * 192 + (((k >> 3) ^ (n & 7)) << 3) + (k & 7);
    WoTs[dst] = f2bf(Wo[k * 192 + n]);
  }
}

// ---------------- K1: qkv GEMM, 128 rows/block, counted-vmcnt barriers ----------------
__global__ __launch_bounds__(512, 4)
void qkv_gemm(const float* __restrict__ X, const unsigned short* __restrict__ WqkvTs,
              const float* __restrict__ bqkv, unsigned short* __restrict__ qkv) {
  __shared__ __align__(16) unsigned short Bs[2][12288];  // weight chunk dbuf (swizzled)
  __shared__ __align__(16) unsigned short scr[8][1152];  // per-wave store bounce
  __shared__ float biasLds[576];                         // qkv bias (kills mid-chunk vmem)

  const int tid = threadIdx.x, w8 = tid >> 6, lane = tid & 63;
  const int g = lane >> 4, c = lane & 15;
  const size_t bm = (size_t)blockIdx.x * 128;
  const f32x4 z = {0.f, 0.f, 0.f, 0.f};

  // stage chunk 0 (async direct to LDS) + bias to LDS
  #pragma unroll
  for (int jj = 0; jj < 3; ++jj)
    gll16(WqkvTs + (w8 * 3 + jj) * 512 + lane * 8, &Bs[0][(w8 * 3 + jj) * 512]);
  for (int j = tid; j < 576; j += 512) biasLds[j] = bqkv[j];

  // A-fragments: 16 rows of X per wave, f32 -> bf16, register-resident
  bf16x8 af[6];
  {
    const float* xr = X + (bm + w8 * 16 + c) * 192;
    #pragma unroll
    for (int ks = 0; ks < 6; ++ks) {
      f32x4 lo = *(const f32x4*)(xr + ks * 32 + g * 8);
      f32x4 hi = *(const f32x4*)(xr + ks * 32 + g * 8 + 4);
      bf16x8 a;
      a[0] = (short)f2bf(lo[0]); a[1] = (short)f2bf(lo[1]);
      a[2] = (short)f2bf(lo[2]); a[3] = (short)f2bf(lo[3]);
      a[4] = (short)f2bf(hi[0]); a[5] = (short)f2bf(hi[1]);
      a[6] = (short)f2bf(hi[2]); a[7] = (short)f2bf(hi[3]);
      af[ks] = a;
    }
  }
  asm volatile("s_waitcnt vmcnt(0)\n\ts_barrier" ::: "memory");  // chunk 0 + bias ready
  __builtin_amdgcn_sched_barrier(0);

  unsigned short* sw = scr[w8];
  for (int nc = 0; nc < 9; ++nc) {
    const int cur = nc & 1;
    if (nc < 8) {  // async-stage next chunk; stays in flight until the counted barrier
      #pragma unroll
      for (int jj = 0; jj < 3; ++jj)
        gll16(WqkvTs + (nc + 1) * 12288 + (w8 * 3 + jj) * 512 + lane * 8,
              &Bs[cur ^ 1][(w8 * 3 + jj) * 512]);
    }
    f32x4 acc[4] = {z, z, z, z};
    #pragma unroll
    for (int ks = 0; ks < 6; ++ks) {
      #pragma unroll
      for (int nf = 0; nf < 4; ++nf) {
        const bf16x8 bv = *(const bf16x8*)(
            &Bs[cur][(nf * 16 + c) * 192 + (((ks * 4 + g) ^ (c & 7)) << 3)]);
        acc[nf] = MFMA(af[ks], bv, acc[nf]);
      }
    }
    // bias (LDS) + bounce -> coalesced 16B stores
    #pragma unroll
    for (int nf = 0; nf < 4; ++nf) {
      const float bb = biasLds[nc * 64 + nf * 16 + c];
      #pragma unroll
      for (int r = 0; r < 4; ++r)
        sw[(4 * g + r) * 72 + nf * 16 + c] = f2bf(acc[nf][r] + bb);
    }
    uint4 o0 = *(const uint4*)(sw + c * 72 + g * 8);
    uint4 o1 = *(const uint4*)(sw + c * 72 + 32 + g * 8);
    unsigned short* qp = qkv + (bm + w8 * 16 + c) * 576 + nc * 64;
    *(uint4*)(qp + g * 8)      = o0;
    *(uint4*)(qp + 32 + g * 8) = o1;

    if (nc < 8) {
      // outstanding (oldest->newest): [old stores, gll x3, new stores x2].
      // vmcnt(2): retire gll (Bs[cur^1] ready for all waves after barrier),
      // leave the 2 fresh qkv stores in flight across the barrier.
      asm volatile("s_waitcnt vmcnt(2)\n\ts_barrier" ::: "memory");
      __builtin_amdgcn_sched_barrier(0);
    }
  }
}

// ---------------- K2: windowed attention ----------------
// grid 4096 (1 window), 512 threads. Wave (mt, hw): heads hw*3..hw*3+2.
// Reads Q/K/V from qkv; writes attn-out into qkv cols [0,192) (Q is dead).
__global__ __launch_bounds__(512, 4)
void attn_win(unsigned short* __restrict__ qkv, const float* __restrict__ btab) {
  __shared__ __align__(16) unsigned short Ks[64 * 200];   // K rows [tok][d192], padded
  __shared__ __align__(16) unsigned short Vt[192 * 72];   // V^T [d][tok]
  __shared__ __align__(16) unsigned short scr[8][1152];   // per-wave P / O bounce
  __shared__ float biasF[1014];

  const int tid = threadIdx.x, w8 = tid >> 6, lane = tid & 63;
  const int g = lane >> 4, c = lane & 15;
  const int mt = w8 & 3, hw = w8 >> 2;
  const size_t tokbase = (size_t)blockIdx.x * 49;
  const f32x4 z = {0.f, 0.f, 0.f, 0.f};

  for (int j = tid; j < 1014; j += 512) biasF[j] = btab[j];
  for (int j = tid; j < 360; j += 512) {      // zero K pad rows 49..63
    uint4 zz = {0, 0, 0, 0};
    *(uint4*)(&Ks[(49 + j / 24) * 200 + (j % 24) * 8]) = zz;
  }
  for (int j = tid; j < 2880; j += 512) Vt[(j / 15) * 72 + 49 + j % 15] = 0;  // V^T pad cols
  for (int j = tid; j < 1176; j += 512) {     // K rows: straight copy
    int row = j / 24, ch = j % 24;
    *(uint4*)(&Ks[row * 200 + ch * 8]) =
        *(const uint4*)(qkv + (tokbase + row) * 576 + 192 + ch * 8);
  }
  for (int j = tid; j < 1176; j += 512) {     // V: transpose-scatter, rotated (3-way)
    int row = j / 24, ch = j % 24;
    uint4 v = *(const uint4*)(qkv + (tokbase + row) * 576 + 384 + ch * 8);
    const unsigned short* e = (const unsigned short*)&v;
    #pragma unroll
    for (int m = 0; m < 8; ++m) {
      int k = (ch + m) & 7;
      Vt[(ch * 8 + k) * 72 + row] = e[k];
    }
  }

  const int qbase = mt * 16;
  const int q = qbase + c;
  const bool qvalid = q < 49;
  const int qc = qvalid ? q : 48;

  // hoist ALL per-head Q loads before the head loop (AO stores alias qkv ->
  // compiler cannot hoist these itself; serial per-head L2 latency otherwise)
  bf16x8 bqh[3];
  #pragma unroll
  for (int hi = 0; hi < 3; ++hi)
    bqh[hi] = *(const bf16x8*)(qkv + (tokbase + qc) * 576 + (hw * 3 + hi) * 32 + g * 8);

  __syncthreads();  // the only barrier

  const int qoff6 = ((6 - qc / 7) * 13 + (6 - qc % 7)) * 6;
  int kb6[16];
  #pragma unroll
  for (int i = 0; i < 16; ++i) {
    int k = (i >> 2) * 16 + g * 4 + (i & 3);
    int kk = k < 49 ? k : 48;
    kb6[i] = ((kk / 7) * 13 + (kk % 7)) * 6;
  }
  unsigned short* Pw = scr[w8];

  #pragma unroll
  for (int hi = 0; hi < 3; ++hi) {
    const int h = hw * 3 + hi;
    const bf16x8 bq = bqh[hi];
    const int cofs = h * 32 + g * 8;
    f32x4 s0 = MFMA(*(const bf16x8*)(Ks + (c) * 200 + cofs), bq, z);
    f32x4 s1 = MFMA(*(const bf16x8*)(Ks + (16 + c) * 200 + cofs), bq, z);
    f32x4 s2 = MFMA(*(const bf16x8*)(Ks + (32 + c) * 200 + cofs), bq, z);
    f32x4 s3 = MFMA(*(const bf16x8*)(Ks + (48 + c) * 200 + cofs), bq, z);

    // softmax: lane holds S^T[k=16t+4g+r][q=qbase+c]  (verified layout)
    float p[16];
    float mx = -3e38f;
    #pragma unroll
    for (int i = 0; i < 16; ++i) {
      const int t = i >> 2, r = i & 3;
      const int k = t * 16 + g * 4 + r;
      const float sv = (t == 0) ? s0[r] : (t == 1) ? s1[r] : (t == 2) ? s2[r] : s3[r];
      const float b = biasF[kb6[i] + qoff6 + h];
      const float lg = (qvalid && (k < 49)) ? fmaf(sv, SCALE, b) : -1e30f;
      p[i] = lg;
      mx = fmaxf(mx, lg);
    }
    mx = fmaxf(mx, __shfl_xor(mx, 16));
    mx = fmaxf(mx, __shfl_xor(mx, 32));
    float sum = 0.f;
    #pragma unroll
    for (int i = 0; i < 16; ++i) { p[i] = __expf(p[i] - mx); sum += p[i]; }
    sum += __shfl_xor(sum, 16);
    sum += __shfl_xor(sum, 32);
    const float inv = 1.0f / sum;
    #pragma unroll
    for (int t = 0; t < 4; ++t) {
      u16x4 pkv;
      #pragma unroll
      for (int r = 0; r < 4; ++r) pkv[r] = f2bf(p[t * 4 + r] * inv);
      *(u16x4*)(Pw + c * 72 + t * 16 + g * 4) = pkv;  // P[q-local=c][k]
    }

    // PV: A = P (wave-private), B = Vt[d][tok]
    f32x4 o0 = z, o1 = z;
    #pragma unroll
    for (int ks = 0; ks < 2; ++ks) {
      const bf16x8 ap = *(const bf16x8*)(Pw + c * 72 + ks * 32 + g * 8);
      const bf16x8 v0 = *(const bf16x8*)(Vt + (h * 32 + c) * 72 + ks * 32 + g * 8);
      const bf16x8 v1 = *(const bf16x8*)(Vt + (h * 32 + 16 + c) * 72 + ks * 32 + g * 8);
      o0 = MFMA(ap, v0, o0);
      o1 = MFMA(ap, v1, o1);
    }
    #pragma unroll
    for (int r = 0; r < 4; ++r) {
      Pw[(4 * g + r) * 72 + c]      = f2bf(o0[r]);
      Pw[(4 * g + r) * 72 + 16 + c] = f2bf(o1[r]);
    }
    uint4 ov = *(const uint4*)(Pw + c * 72 + g * 8);
    if (qvalid)
      *(uint4*)(qkv + (tokbase + q) * 576 + h * 32 + g * 8) = ov;
  }
}

// ---------------- K3: output projection, 128 rows/block, async-LDS Wo staging ----------------
__global__ __launch_bounds__(512, 4)
void out_gemm(const unsigned short* __restrict__ qkv, const unsigned short* __restrict__ WoTs,
              const float* __restrict__ bo, float* __restrict__ out) {
  __shared__ __align__(16) unsigned short Ws[192 * 192];  // 73.7 KB, UNPADDED (swizzled)

  const int tid = threadIdx.x, w8 = tid >> 6, lane = tid & 63;
  const int g = lane >> 4, c = lane & 15;
  const size_t bm = (size_t)blockIdx.x * 128;
  const f32x4 z = {0.f, 0.f, 0.f, 0.f};

  // stage all of Wo async: 72 wave-chunks of 1 KB, linear LDS dest
  #pragma unroll
  for (int jj = 0; jj < 9; ++jj)
    gll16(WoTs + (w8 * 9 + jj) * 512 + lane * 8, &Ws[(w8 * 9 + jj) * 512]);

  // A-fragments while the staging flies
  bf16x8 af[6];
  #pragma unroll
  for (int ks = 0; ks < 6; ++ks)
    af[ks] = *(const bf16x8*)(qkv + (bm + w8 * 16 + c) * 576 + ks * 32 + g * 8);
  __syncthreads();  // drains vmcnt (gll) before reads

  #pragma unroll
  for (int nf = 0; nf < 12; ++nf) {
    const int col = nf * 16 + c;
    f32x4 acc = z;
    #pragma unroll
    for (int ks = 0; ks < 6; ++ks) {
      const bf16x8 bv = *(const bf16x8*)(
          &Ws[col * 192 + (((ks * 4 + g) ^ (c & 7)) << 3)]);
      acc = MFMA(af[ks], bv, acc);
    }
    const float bb = bo[col];
    #pragma unroll
    for (int r = 0; r < 4; ++r)
      out[(bm + w8 * 16 + 4 * g + r) * 192 + col] = acc[r] + bb;
  }
}

extern "C" void kernel_launch(void* const* d_in, const int* in_sizes, int n_in,
                              void* d_out, int out_size, void* d_ws, size_t ws_size,
                              hipStream_t stream) {
  (void)in_sizes; (void)n_in; (void)out_size; (void)ws_size;
  const float* X    = (const float*)d_in[0];
  const float* Wqkv = (const float*)d_in[1];
  const float* bqkv = (const float*)d_in[2];
  const float* Wo   = (const float*)d_in[3];
  const float* bo   = (const float*)d_in[4];
  const float* btab = (const float*)d_in[5];

  unsigned short* WqkvTs = (unsigned short*)d_ws;  // 576*192 bf16 (swizzled layout)
  unsigned short* WoTs   = WqkvTs + 576 * 192;     // 192*192 bf16 (swizzled layout)
  unsigned short* qkv    = WoTs + 192 * 192;       // 200704*576 bf16 (231 MB)

  wprep<<<432, 256, 0, stream>>>(Wqkv, Wo, WqkvTs, WoTs);
  qkv_gemm<<<1568, 512, 0, stream>>>(X, WqkvTs, bqkv, qkv);
  attn_win<<<4096, 512, 0, stream>>>(qkv, btab);
  out_gemm<<<1568, 512, 0, stream>>>(qkv, WoTs, bo, (float*)d_out);
}